// Round 5
// baseline (737.462 us; speedup 1.0000x reference)
//
#include <hip/hip_runtime.h>

static constexpr int   kBatch   = 2097152;
static constexpr float kActScale = 1.0f / 12.0f;
static constexpr float kAct2     = 1.0f / 6.0f;   // 2*ACT_SCALE

// Device-global table:
// [0,1024)    spA0   (softplus(raw_A_0), row-major [i][j])
// [1024,2048) spA1
// [2048,3072) spA0T  (transposed)
// [3072,4096) spA1T
// [4096,4128) spAout
// [4128]      cref   (dW/dI1 at z0 = 0)
__device__ float g_tab[4136];

__device__ __forceinline__ float rcp_f(float x) { return __fdividef(1.0f, x); }

__device__ __forceinline__ float sp_only(float x) {
    float e = __expf(-fabsf(x));
    return fmaxf(x, 0.0f) + __logf(1.0f + e);
}
__device__ __forceinline__ float sig_only(float x) {
    float e = __expf(-fabsf(x));
    float r = rcp_f(1.0f + e);
    return (x >= 0.0f) ? r : e * r;
}
__device__ __forceinline__ float sp_sig(float x, float& sig) {
    float e  = __expf(-fabsf(x));
    float oe = 1.0f + e;
    float r  = rcp_f(oe);
    sig = (x >= 0.0f) ? r : e * r;
    return fmaxf(x, 0.0f) + __logf(oe);
}

// ---------------- prep: softplus tables + reference-gradient constant --------
__global__ __launch_bounds__(256) void icnn_prep(
    const float* __restrict__ rawA0, const float* __restrict__ rawA1,
    const float* __restrict__ rawAout,
    const float* __restrict__ W1,  const float* __restrict__ b1,
    const float* __restrict__ Wc0, const float* __restrict__ bc0,
    const float* __restrict__ Wc1, const float* __restrict__ bc1,
    const float* __restrict__ wout)
{
    __shared__ float sA0[1024], sA1[1024], sAout[32];
    const int t = threadIdx.x;
    for (int k = t; k < 1024; k += 256) { float v = sp_only(rawA0[k]); sA0[k] = v; g_tab[k] = v; }
    for (int k = t; k < 1024; k += 256) { float v = sp_only(rawA1[k]); sA1[k] = v; g_tab[1024 + k] = v; }
    if (t < 32) { float v = sp_only(rawAout[t]); sAout[t] = v; g_tab[4096 + t] = v; }
    __syncthreads();
    for (int k = t; k < 1024; k += 256) g_tab[2048 + k] = sA0[(k & 31) * 32 + (k >> 5)];
    for (int k = t; k < 1024; k += 256) g_tab[3072 + k] = sA1[(k & 31) * 32 + (k >> 5)];

    if (t < 32) {
        const int i = t;
        float sa, sc0v;
        float zi = sp_sig(b1[i], sa);
        float u = 0.0f;
        for (int j = 0; j < 32; j++) u = fmaf(sA0[i * 32 + j], __shfl(zi, j, 64), u);
        float su; float t0 = sp_sig(u, su);
        float d0 = kAct2 * t0 * su;
        float spc = sp_sig(bc0[i], sc0v);
        float zn = fmaf(kActScale * t0, t0, spc);
        float u1 = 0.0f;
        for (int j = 0; j < 32; j++) u1 = fmaf(sA1[i * 32 + j], __shfl(zn, j, 64), u1);
        float su1; float t1 = sp_sig(u1, su1);
        float d1 = sAout[i] * kAct2 * t1 * su1;
        float contrib = Wc1[2 * i] * sAout[i] * sig_only(bc1[i]);
        float g = 0.0f;
        for (int j = 0; j < 32; j++) g = fmaf(sA1[j * 32 + i], __shfl(d1, j, 64), g);
        contrib = fmaf(Wc0[2 * i], g * sc0v, contrib);
        float gu0 = g * d0;
        float ga = 0.0f;
        for (int j = 0; j < 32; j++) ga = fmaf(sA0[j * 32 + i], __shfl(gu0, j, 64), ga);
        ga *= sa;
        contrib = fmaf(W1[2 * i], ga, contrib);
        for (int off = 16; off >= 1; off >>= 1)
            contrib += __shfl_down(contrib, off, 32);
        if (i == 0) g_tab[4128] = wout[0] + contrib;
    }
}

// ---------------- main: outer-product scatter, 2 register banks --------------
// R4 post-mortem: serial DOT chains -> scheduler interleaving -> pressure
// spike -> spills (VGPR=84 + 61 MB scratch->HBM). This version makes low
// pressure STRUCTURAL: every matvec is j-outer scatter (32 independent
// accumulators, input value consumed immediately), only two 32-scalar banks
// (r, s) are ever live, and d0 (the one long-range array) lives in LDS
// ([32][256] = 32 KB/block, bank-conflict-free, 4 blocks/CU).

#define RPT32(M) M(0) M(1) M(2) M(3) M(4) M(5) M(6) M(7) \
                 M(8) M(9) M(10) M(11) M(12) M(13) M(14) M(15) \
                 M(16) M(17) M(18) M(19) M(20) M(21) M(22) M(23) \
                 M(24) M(25) M(26) M(27) M(28) M(29) M(30) M(31)

// bank_k += col[k] * v   (32 independent FMAs; col is a contiguous,
// wave-uniform table row -> s_load + FMA-with-SGPR-operand)
#define SCAT32(bank, col, v) \
  bank##_0  = fmaf((col)[0],  (v), bank##_0 ); bank##_1  = fmaf((col)[1],  (v), bank##_1 ); \
  bank##_2  = fmaf((col)[2],  (v), bank##_2 ); bank##_3  = fmaf((col)[3],  (v), bank##_3 ); \
  bank##_4  = fmaf((col)[4],  (v), bank##_4 ); bank##_5  = fmaf((col)[5],  (v), bank##_5 ); \
  bank##_6  = fmaf((col)[6],  (v), bank##_6 ); bank##_7  = fmaf((col)[7],  (v), bank##_7 ); \
  bank##_8  = fmaf((col)[8],  (v), bank##_8 ); bank##_9  = fmaf((col)[9],  (v), bank##_9 ); \
  bank##_10 = fmaf((col)[10], (v), bank##_10); bank##_11 = fmaf((col)[11], (v), bank##_11); \
  bank##_12 = fmaf((col)[12], (v), bank##_12); bank##_13 = fmaf((col)[13], (v), bank##_13); \
  bank##_14 = fmaf((col)[14], (v), bank##_14); bank##_15 = fmaf((col)[15], (v), bank##_15); \
  bank##_16 = fmaf((col)[16], (v), bank##_16); bank##_17 = fmaf((col)[17], (v), bank##_17); \
  bank##_18 = fmaf((col)[18], (v), bank##_18); bank##_19 = fmaf((col)[19], (v), bank##_19); \
  bank##_20 = fmaf((col)[20], (v), bank##_20); bank##_21 = fmaf((col)[21], (v), bank##_21); \
  bank##_22 = fmaf((col)[22], (v), bank##_22); bank##_23 = fmaf((col)[23], (v), bank##_23); \
  bank##_24 = fmaf((col)[24], (v), bank##_24); bank##_25 = fmaf((col)[25], (v), bank##_25); \
  bank##_26 = fmaf((col)[26], (v), bank##_26); bank##_27 = fmaf((col)[27], (v), bank##_27); \
  bank##_28 = fmaf((col)[28], (v), bank##_28); bank##_29 = fmaf((col)[29], (v), bank##_29); \
  bank##_30 = fmaf((col)[30], (v), bank##_30); bank##_31 = fmaf((col)[31], (v), bank##_31);

__global__ __launch_bounds__(256, 4) void icnn_main(
    const float* __restrict__ eps,
    const float* __restrict__ W1,  const float* __restrict__ b1,
    const float* __restrict__ Wc0, const float* __restrict__ bc0,
    const float* __restrict__ Wc1, const float* __restrict__ bc1,
    const float* __restrict__ wout,
    float* __restrict__ out)
{
    __shared__ float s_d0[32 * 256];          // [unit][thread], 32 KB
    const int tid = threadIdx.x;
    const int row = blockIdx.x * 256 + tid;

    const float e11 = eps[row * 3 + 0];
    const float e22 = eps[row * 3 + 1];
    const float e12 = eps[row * 3 + 2];
    const float x1 = e11 + e22;
    const float x2 = e11 * e11 + 2.0f * e12 * e12 + e22 * e22;

    const float* __restrict__ A0   = g_tab;
    const float* __restrict__ A1   = g_tab + 1024;
    const float* __restrict__ A0T  = g_tab + 2048;
    const float* __restrict__ A1T  = g_tab + 3072;
    const float* __restrict__ aout = g_tab + 4096;

    float g0 = wout[0], gq = wout[1];

#define DECL_R(i) float r_##i = 0.0f;
#define DECL_S(i) float s_##i = 0.0f;
    RPT32(DECL_R) RPT32(DECL_S)

    // ---- P1: r = A0·z, z generated on the fly (column j of A0 = row j of A0T)
#define P1(j) { float a = fmaf(W1[2*(j)], x1, fmaf(W1[2*(j)+1], x2, b1[(j)])); \
                float zj = sp_only(a); \
                SCAT32(r, A0T + (j)*32, zj) }
    RPT32(P1)

    // ---- P2: consume r_i = u_i -> d0 (LDS), zn; scatter zn into s = A1·zn
    //          (column i of A1 = row i of A1T)
#define P2(i) { float su; float t = sp_sig(r_##i, su); \
                s_d0[(i)*256 + tid] = kAct2 * t * su; \
                float c = fmaf(Wc0[2*(i)], x1, fmaf(Wc0[2*(i)+1], x2, bc0[(i)])); \
                float znv = fmaf(kActScale * t, t, sp_only(c)); \
                SCAT32(s, A1T + (i)*32, znv) }
    RPT32(P2)

    // reset bank r for reuse as gg accumulator
#define RZ(i) r_##i = 0.0f;
    RPT32(RZ)

    // ---- P3: consume s_j = u1_j -> d1_j; fold c1-skip; scatter d1 into
    //          r = A1^T·d1 (column j of A1T = row j of A1)
#define P3(j) { float su; float t = sp_sig(s_##j, su); \
                float d1v = aout[(j)] * kAct2 * t * su; \
                float c = fmaf(Wc1[2*(j)], x1, fmaf(Wc1[2*(j)+1], x2, bc1[(j)])); \
                float w = aout[(j)] * sig_only(c); \
                g0 = fmaf(Wc1[2*(j)], w, g0); \
                gq = fmaf(Wc1[2*(j)+1], w, gq); \
                SCAT32(r, A1 + (j)*32, d1v) }
    RPT32(P3)

#define SZ(i) s_##i = 0.0f;
    RPT32(SZ)

    // ---- P4: consume r_i = (A1^T d1)_i; fold c0-skip (different association
    //          than P2 to block CSE); h = r_i * d0_i (LDS); scatter h into
    //          s = A0^T·h (column i of A0T = row i of A0)
#define P4(i) { float acc = r_##i; \
                float c = fmaf(Wc0[2*(i)+1], x2, fmaf(Wc0[2*(i)], x1, bc0[(i)])); \
                float w = acc * sig_only(c); \
                g0 = fmaf(Wc0[2*(i)], w, g0); \
                gq = fmaf(Wc0[2*(i)+1], w, gq); \
                float h = acc * s_d0[(i)*256 + tid]; \
                SCAT32(s, A0 + (i)*32, h) }
    RPT32(P4)

    // ---- P5: consume s_i; recompute a_i (different association than P1);
    //          final fold into g0/gq
#define P5(i) { float a = fmaf(W1[2*(i)+1], x2, fmaf(W1[2*(i)], x1, b1[(i)])); \
                float ga = s_##i * sig_only(a); \
                g0 = fmaf(W1[2*(i)], ga, g0); \
                gq = fmaf(W1[2*(i)+1], ga, gq); }
    RPT32(P5)

    const float cref = g_tab[4128];
    const float dI1 = g0 - cref;
    const float dI2 = gq;
    out[row * 3 + 0] = fmaf(2.0f * e11, dI2, dI1);
    out[row * 3 + 1] = fmaf(2.0f * e22, dI2, dI1);
    out[row * 3 + 2] = 2.0f * e12 * dI2;
}

extern "C" void kernel_launch(void* const* d_in, const int* in_sizes, int n_in,
                              void* d_out, int out_size, void* d_ws, size_t ws_size,
                              hipStream_t stream)
{
    (void)in_sizes; (void)n_in; (void)out_size; (void)d_ws; (void)ws_size;
    const float* eps    = (const float*)d_in[0];
    const float* W1     = (const float*)d_in[1];
    const float* b1     = (const float*)d_in[2];
    const float* rawA0  = (const float*)d_in[3];
    const float* rawA1  = (const float*)d_in[4];
    const float* Wc0    = (const float*)d_in[5];
    const float* bc0    = (const float*)d_in[6];
    const float* Wc1    = (const float*)d_in[7];
    const float* bc1    = (const float*)d_in[8];
    const float* rawAout= (const float*)d_in[9];
    const float* wout   = (const float*)d_in[10];
    float* out = (float*)d_out;

    icnn_prep<<<1, 256, 0, stream>>>(rawA0, rawA1, rawAout, W1, b1, Wc0, bc0, Wc1, bc1, wout);
    icnn_main<<<kBatch / 256, 256, 0, stream>>>(eps, W1, b1, Wc0, bc0, Wc1, bc1, wout, out);
}

// Round 6
// 563.248 us; speedup vs baseline: 1.3093x; 1.3093x over previous
//
#include <hip/hip_runtime.h>

static constexpr int   kBatch   = 2097152;
static constexpr int   H        = 32;
static constexpr float kActScale = 1.0f / 12.0f;
static constexpr float kAct2     = 1.0f / 6.0f;   // 2*ACT_SCALE

// Device-global table:
// [0,1024)    spA0        (softplus(raw_A_0), row-major [i][j])
// [1024,2048) spA1
// [2048,3072) spA0T       (transposed copy for backward)
// [3072,4096) spA1T
// [4096,4128) spAout      (softplus(raw_A_out))
// [4128]      cref        (dW/dI1 at z0 = 0)
__device__ float g_tab[4136];

__device__ __forceinline__ float rcp_f(float x) { return __fdividef(1.0f, x); }

__device__ __forceinline__ float sp_only(float x) {
    float e = __expf(-fabsf(x));
    return fmaxf(x, 0.0f) + __logf(1.0f + e);
}
__device__ __forceinline__ float sig_only(float x) {
    float e = __expf(-fabsf(x));
    float r = rcp_f(1.0f + e);
    return (x >= 0.0f) ? r : e * r;
}
// softplus(x), and sigmoid(x) via out-param. Stable for |x| up to hundreds.
__device__ __forceinline__ float sp_sig(float x, float& sig) {
    float e  = __expf(-fabsf(x));
    float oe = 1.0f + e;
    float r  = rcp_f(oe);
    sig = (x >= 0.0f) ? r : e * r;
    return fmaxf(x, 0.0f) + __logf(oe);
}

// ---------------- prep: softplus tables + reference-gradient constant --------
__global__ __launch_bounds__(256) void icnn_prep(
    const float* __restrict__ rawA0, const float* __restrict__ rawA1,
    const float* __restrict__ rawAout,
    const float* __restrict__ W1,  const float* __restrict__ b1,
    const float* __restrict__ Wc0, const float* __restrict__ bc0,
    const float* __restrict__ Wc1, const float* __restrict__ bc1,
    const float* __restrict__ wout)
{
    __shared__ float sA0[1024], sA1[1024], sAout[32];
    const int t = threadIdx.x;
    for (int k = t; k < 1024; k += 256) { float v = sp_only(rawA0[k]); sA0[k] = v; g_tab[k] = v; }
    for (int k = t; k < 1024; k += 256) { float v = sp_only(rawA1[k]); sA1[k] = v; g_tab[1024 + k] = v; }
    if (t < 32) { float v = sp_only(rawAout[t]); sAout[t] = v; g_tab[4096 + t] = v; }
    __syncthreads();
    // transposed copies (contiguous scalar loads in the backward matvecs)
    for (int k = t; k < 1024; k += 256) g_tab[2048 + k] = sA0[(k & 31) * 32 + (k >> 5)];
    for (int k = t; k < 1024; k += 256) g_tab[3072 + k] = sA1[(k & 31) * 32 + (k >> 5)];

    // reference gradient dW/dI1 at z0 = (0,0), computed by wave-0 lanes 0..31
    if (t < 32) {
        const int i = t;
        float sa, sc0v;
        float zi = sp_sig(b1[i], sa);
        float u = 0.0f;
        for (int j = 0; j < 32; j++) u = fmaf(sA0[i * 32 + j], __shfl(zi, j, 64), u);
        float su; float t0 = sp_sig(u, su);
        float d0 = kAct2 * t0 * su;
        float spc = sp_sig(bc0[i], sc0v);
        float zn = fmaf(kActScale * t0, t0, spc);
        float u1 = 0.0f;
        for (int j = 0; j < 32; j++) u1 = fmaf(sA1[i * 32 + j], __shfl(zn, j, 64), u1);
        float su1; float t1 = sp_sig(u1, su1);
        float d1 = sAout[i] * kAct2 * t1 * su1;
        float contrib = Wc1[2 * i] * sAout[i] * sig_only(bc1[i]);
        float g = 0.0f;
        for (int j = 0; j < 32; j++) g = fmaf(sA1[j * 32 + i], __shfl(d1, j, 64), g);
        contrib = fmaf(Wc0[2 * i], g * sc0v, contrib);
        float gu0 = g * d0;
        float ga = 0.0f;
        for (int j = 0; j < 32; j++) ga = fmaf(sA0[j * 32 + i], __shfl(gu0, j, 64), ga);
        ga *= sa;
        contrib = fmaf(W1[2 * i], ga, contrib);
        for (int off = 16; off >= 1; off >>= 1)
            contrib += __shfl_down(contrib, off, 32);
        if (i == 0) g_tab[4128] = wout[0] + contrib;
    }
}

// ---------------- main: one thread per row, fused fwd+bwd --------------------
// R5 post-mortem: VGPR_Count landed on occupancy boundaries (60/64/84) every
// round -- the GCN scheduler TARGETS max occupancy (8 waves/SIMD = 64 VGPR)
// and spills the ~110-float live state to scratch to get there.
// __launch_bounds__'s 2nd arg only sets a MINIMUM waves/EU (budget cap).
// Fix: amdgpu_waves_per_eu(3,3) pins min=max=3 -> 170-VGPR budget and no
// incentive to squeeze. Structure identical to R3 (clean A/B on one knob).
__global__ __launch_bounds__(256) __attribute__((amdgpu_waves_per_eu(3, 3)))
void icnn_main(
    const float* __restrict__ eps,
    const float* __restrict__ W1,  const float* __restrict__ b1,
    const float* __restrict__ Wc0, const float* __restrict__ bc0,
    const float* __restrict__ Wc1, const float* __restrict__ bc1,
    const float* __restrict__ wout,
    float* __restrict__ out)
{
    const int row = blockIdx.x * 256 + threadIdx.x;
    if (row >= kBatch) return;

    const float e11 = eps[row * 3 + 0];
    const float e22 = eps[row * 3 + 1];
    const float e12 = eps[row * 3 + 2];
    const float x1 = e11 + e22;
    const float x2 = e11 * e11 + 2.0f * e12 * e12 + e22 * e22;

    const float* __restrict__ A0   = g_tab;
    const float* __restrict__ A1   = g_tab + 1024;
    const float* __restrict__ A0T  = g_tab + 2048;
    const float* __restrict__ A1T  = g_tab + 3072;
    const float* __restrict__ aout = g_tab + 4096;

    float g0 = wout[0], gq = wout[1];

    // ---- L1 forward: z = softplus(W1 z0 + b1). sigmoid recomputed later.
    float z[H];
    #pragma unroll
    for (int i = 0; i < H; i++) {
        float a = fmaf(W1[2 * i], x1, fmaf(W1[2 * i + 1], x2, b1[i]));
        z[i] = sp_only(a);
    }

    // ---- layer 0: u = A0 z; zn = ACT*sp(u)^2 + sp(c0); d0 = dz/du.
    float zn[H], d0[H];
    #pragma unroll
    for (int i = 0; i < H; i++) {
        float u = 0.0f;
        #pragma unroll
        for (int j = 0; j < H; j++) u = fmaf(A0[i * H + j], z[j], u);
        float su; float t = sp_sig(u, su);
        d0[i] = kAct2 * t * su;
        float c = fmaf(Wc0[2 * i], x1, fmaf(Wc0[2 * i + 1], x2, bc0[i]));
        zn[i] = fmaf(kActScale * t, t, sp_only(c));
    }

    // ---- layer 1: d1 = aout .* dz2/du1; fold the c1-skip gradient now.
    float d1[H];
    #pragma unroll
    for (int i = 0; i < H; i++) {
        float u = 0.0f;
        #pragma unroll
        for (int j = 0; j < H; j++) u = fmaf(A1[i * H + j], zn[j], u);
        float su; float t = sp_sig(u, su);
        d1[i] = aout[i] * kAct2 * t * su;
        float c = fmaf(Wc1[2 * i], x1, fmaf(Wc1[2 * i + 1], x2, bc1[i]));
        float w = aout[i] * sig_only(c);
        g0 = fmaf(Wc1[2 * i], w, g0);
        gq = fmaf(Wc1[2 * i + 1], w, gq);
    }

    // ---- backward: acc = (A1^T d1)_i; fold layer-0 skip gradient; gate by d0.
    float g[H];
    #pragma unroll
    for (int i = 0; i < H; i++) {
        float acc = 0.0f;
        #pragma unroll
        for (int j = 0; j < H; j++) acc = fmaf(A1T[i * H + j], d1[j], acc);
        float c = fmaf(Wc0[2 * i + 1], x2, fmaf(Wc0[2 * i], x1, bc0[i]));
        float w = acc * sig_only(c);
        g0 = fmaf(Wc0[2 * i], w, g0);
        gq = fmaf(Wc0[2 * i + 1], w, gq);
        g[i] = acc * d0[i];
    }

    // ---- through A0^T and the first layer (recompute sigmoid(a)).
    #pragma unroll
    for (int i = 0; i < H; i++) {
        float acc = 0.0f;
        #pragma unroll
        for (int j = 0; j < H; j++) acc = fmaf(A0T[i * H + j], g[j], acc);
        float a = fmaf(W1[2 * i + 1], x2, fmaf(W1[2 * i], x1, b1[i]));
        float ga = acc * sig_only(a);
        g0 = fmaf(W1[2 * i], ga, g0);
        gq = fmaf(W1[2 * i + 1], ga, gq);
    }

    const float cref = g_tab[4128];
    const float dI1 = g0 - cref;
    const float dI2 = gq;
    out[row * 3 + 0] = fmaf(2.0f * e11, dI2, dI1);
    out[row * 3 + 1] = fmaf(2.0f * e22, dI2, dI1);
    out[row * 3 + 2] = 2.0f * e12 * dI2;
}

extern "C" void kernel_launch(void* const* d_in, const int* in_sizes, int n_in,
                              void* d_out, int out_size, void* d_ws, size_t ws_size,
                              hipStream_t stream)
{
    (void)in_sizes; (void)n_in; (void)out_size; (void)d_ws; (void)ws_size;
    const float* eps    = (const float*)d_in[0];
    const float* W1     = (const float*)d_in[1];
    const float* b1     = (const float*)d_in[2];
    const float* rawA0  = (const float*)d_in[3];
    const float* rawA1  = (const float*)d_in[4];
    const float* Wc0    = (const float*)d_in[5];
    const float* bc0    = (const float*)d_in[6];
    const float* Wc1    = (const float*)d_in[7];
    const float* bc1    = (const float*)d_in[8];
    const float* rawAout= (const float*)d_in[9];
    const float* wout   = (const float*)d_in[10];
    float* out = (float*)d_out;

    icnn_prep<<<1, 256, 0, stream>>>(rawA0, rawA1, rawAout, W1, b1, Wc0, bc0, Wc1, bc1, wout);
    icnn_main<<<kBatch / 256, 256, 0, stream>>>(eps, W1, b1, Wc0, bc0, Wc1, bc1, wout, out);
}